// Round 12
// baseline (53.627 us; speedup 1.0000x reference)
//
#include <hip/hip_runtime.h>
#include <hip/hip_bf16.h>

// DivEncLayer via MFMA, R12: line-dense LDS staging of x at high occupancy.
// per (b,q): z = W1^T x + b1; out = sum_h w2p*elu(z) + b2p.  B=32768, Q=128, S=8, H=32.
//
// R11 -> R12: Occ 37->61% left the wall at ~50us with HBM pinned at 1.0-1.2 TB/s in
// EVERY per-lane-row-strided variant -> shared per-CU line-miss throttle (each wave-load
// = 32 distinct 4KB-strided lines, 0% L1 hit; ~64 MSHRs x 64B / 600ns = 1.7 TB/s = the
// measured wall). ONE change: stage x via global_load_lds in 1KB-contiguous instructions
// (8-16 lines/instr, 4x fewer line-misses/byte), compute lanes read rows from LDS.
// XOR swizzle (block j <-> row r, same involution both sides per G21) keeps ds_read_b128
// conflict-free. m97 pipeline: stage(c+1) before compute(c), 1 barrier/chunk.
// Block = 8 waves x 128 rows x 16 q; LDS 32KB xbuf + 8.7KB slab -> 3 blocks/CU (75% occ).

#define QN 128
#define SN 8
#define HN 32
#define XROW 1024
#define BN_EPS 1e-3f
#define ROWS_BLK 128
#define CHUNK 32
#define QBLK 16

typedef short bf16x8 __attribute__((ext_vector_type(8)));
typedef float f32x16 __attribute__((ext_vector_type(16)));
typedef unsigned int u32;

typedef __attribute__((address_space(1))) void as1_void;
typedef __attribute__((address_space(3))) void as3_void;

#define WS_A_BYTES (QN * 64 * 16)                 // A[q][lane] 16B (bias in k8, hi lanes)
#define WS_W_OFF   WS_A_BYTES
#define WS_W_BYTES (QN * 32 * 4)                  // w2p[q][half*16+r] (f32, D-reg order)
#define WS_B2_OFF  (WS_W_OFF + WS_W_BYTES)        // b2p[q] (with -sum(w2p) folded)

static __device__ __forceinline__ u32 pkbf(float lo, float hi) {
    union { __hip_bfloat162 h2; u32 u; } c;
    c.h2 = __float22bfloat162_rn(float2{lo, hi});
    return c.u;
}

__global__ void divenc_prep(const float* __restrict__ W1, const float* __restrict__ b1,
                            const float* __restrict__ gamma_, const float* __restrict__ beta_,
                            const float* __restrict__ mmean, const float* __restrict__ mvar,
                            const float* __restrict__ W2, const float* __restrict__ b2,
                            unsigned char* __restrict__ ws)
{
    const int q = blockIdx.x;        // 0..127
    const int m = threadIdx.x;       // 0..63

    u32 d0 = 0, d1 = 0, d2 = 0, d3 = 0;
    if (m < 32) {                    // A[m][k0..7] = W1[q][k][m]
        d0 = pkbf(W1[(q*SN + 0)*HN + m], W1[(q*SN + 1)*HN + m]);
        d1 = pkbf(W1[(q*SN + 2)*HN + m], W1[(q*SN + 3)*HN + m]);
        d2 = pkbf(W1[(q*SN + 4)*HN + m], W1[(q*SN + 5)*HN + m]);
        d3 = pkbf(W1[(q*SN + 6)*HN + m], W1[(q*SN + 7)*HN + m]);
    } else {                         // A[m][k8] = b1[m] (bias; B k8 = 1.0), k9-15 = 0
        d0 = pkbf(b1[q*HN + (m - 32)], 0.f);
    }
    ((uint4*)ws)[q*64 + m] = uint4{d0, d1, d2, d3};

    float* wsW  = (float*)(ws + WS_W_OFF);
    float* wsB2 = (float*)(ws + WS_B2_OFF);
    if (m < 32) {                    // D-reg order: h = (r&3) + 8*(r>>2) + 4*half
        const int half = m >> 4, r = m & 15;
        const int h = (r & 3) + 8*(r >> 2) + 4*half;
        float inv = gamma_[q*HN+h] * rsqrtf(mvar[q*HN+h] + BN_EPS);
        wsW[q*32 + m] = inv * W2[q*HN + h];
    }
    if (m == 0) {
        float acc = b2[q];
        for (int h = 0; h < HN; ++h) {
            float inv = gamma_[q*HN+h] * rsqrtf(mvar[q*HN+h] + BN_EPS);
            float w2p = inv * W2[q*HN + h];
            acc += (beta_[q*HN+h] - mmean[q*HN+h]*inv) * W2[q*HN+h] - w2p;  // fold -sum(w2p)
        }
        wsB2[q] = acc;
    }
}

// Stage chunk c (32 rows x 512B) into buf: 16 instrs x 1KB contiguous; wave wv issues 2.
// Instr i covers chunk rows {2i, 2i+1}: lanes 0-31 -> row 2i, lanes 32-63 -> row 2i+1.
// Source XOR-swizzle: phys 16B slot l receives logical block l^r (involution; the
// ds_read applies the same XOR). LDS dest stays linear (global_load_lds requirement).
__device__ __forceinline__
void stage_chunk(const float* __restrict__ x, u32* buf,
                 int b0, int q0, int c, int wv, int lane)
{
    #pragma unroll
    for (int k = 0; k < 2; ++k) {
        const int i  = wv * 2 + k;               // 0..15
        const int r  = i * 2 + (lane >> 5);      // chunk-local row 0..31
        const int jl = (lane & 31) ^ r;          // logical 16B-block index for phys slot
        const float* src = x + (size_t)(b0 + c * CHUNK + r) * XROW + q0 * SN + jl * 4;
        u32* dst = buf + i * 256;                // wave-uniform; HW adds lane*16B
        __builtin_amdgcn_global_load_lds((const as1_void*)src, (as3_void*)dst, 16, 0, 0);
    }
}

__global__ __launch_bounds__(512, 8)
void divenc_mfma(const float* __restrict__ x, const unsigned char* __restrict__ ws,
                 float* __restrict__ out)
{
    const int tid  = threadIdx.x;
    const int lane = tid & 63;
    const int wv   = tid >> 6;       // 0..7
    const int half = lane >> 5;
    const int bl   = lane & 31;
    const bool hi  = lane >= 32;
    const int b0   = blockIdx.x * ROWS_BLK;
    const int q0   = blockIdx.y * QBLK;

    const uint4* wsA  = (const uint4*)ws;
    const float* wsW  = (const float*)(ws + WS_W_OFF);
    const float* wsB2 = (const float*)(ws + WS_B2_OFF);

    __shared__ u32   xbuf[2][CHUNK * 128];   // 2 x 16 KiB
    __shared__ float slab[ROWS_BLK][QBLK + 1];

    stage_chunk(x, xbuf[0], b0, q0, 0, wv, lane);

    #pragma unroll 1
    for (int c = 0; c < 4; ++c) {
        __syncthreads();                 // vmcnt drained -> stage(c) data visible to all

        if (c < 3) stage_chunk(x, xbuf[(c + 1) & 1], b0, q0, c + 1, wv, lane);

        const u32* xb = xbuf[c & 1];

        #pragma unroll
        for (int qg = 0; qg < 2; ++qg) {
            const int qloc = qg * 8 + wv;        // 0..15
            const int q    = q0 + qloc;

            union { uint4 u; bf16x8 v; } A;
            A.u = wsA[q * 64 + lane];            // L2-hot weights

            float w2r[16];
            const float* wp_ = wsW + q * 32 + half * 16;
            #pragma unroll
            for (int r = 0; r < 16; ++r) w2r[r] = wp_[r];
            const float b2p = wsB2[q];

            // lane's row bl: logical blocks 2qloc/2qloc+1 at phys = logical ^ bl
            const u32* rowp = xb + bl * 128;
            const uint4 xw0 = *(const uint4*)(rowp + (((2 * qloc)     ^ bl) * 4));
            const uint4 xw1 = *(const uint4*)(rowp + (((2 * qloc + 1) ^ bl) * 4));

            union { uint4 u; bf16x8 v; } B;      // hi: k8 = bf16(1.0) bias, k9-15 = 0
            B.u = uint4{
                hi ? 0x00003F80u : pkbf(__uint_as_float(xw0.x), __uint_as_float(xw0.y)),
                hi ? 0u          : pkbf(__uint_as_float(xw0.z), __uint_as_float(xw0.w)),
                hi ? 0u          : pkbf(__uint_as_float(xw1.x), __uint_as_float(xw1.y)),
                hi ? 0u          : pkbf(__uint_as_float(xw1.z), __uint_as_float(xw1.w)) };

            const f32x16 Z = {0.f,0.f,0.f,0.f,0.f,0.f,0.f,0.f,
                              0.f,0.f,0.f,0.f,0.f,0.f,0.f,0.f};
            f32x16 D = __builtin_amdgcn_mfma_f32_32x32x16_bf16(A.v, B.v, Z, 0, 0, 0);

            float p0 = 0.f, p1 = 0.f;            // elu = E + R - 1 (the -1 is in b2p)
            #pragma unroll
            for (int r = 0; r < 16; ++r) {
                const float z = D[r];
                const float E = __expf(fminf(z, 0.f));   // z>0 -> 1
                const float R = fmaxf(z, 0.f);
                p0 = fmaf(E, w2r[r], p0);
                p1 = fmaf(R, w2r[r], p1);
            }
            float p = p0 + p1;
            p += __shfl_xor(p, 32);              // combine h-halves (same b-col)
            if (!hi) slab[c * CHUNK + bl][qloc] = p + b2p;
        }
    }

    __syncthreads();

    // dump 128 rows x 16 q; 512 threads x 16B
    {
        const int row = tid >> 2;
        const int c4  = (tid & 3) * 4;
        float4 vv;
        vv.x = slab[row][c4 + 0];
        vv.y = slab[row][c4 + 1];
        vv.z = slab[row][c4 + 2];
        vv.w = slab[row][c4 + 3];
        *(float4*)(out + (size_t)(b0 + row) * QN + q0 + c4) = vv;
    }
}

extern "C" void kernel_launch(void* const* d_in, const int* in_sizes, int n_in,
                              void* d_out, int out_size, void* d_ws, size_t ws_size,
                              hipStream_t stream) {
    const float* x      = (const float*)d_in[0];
    const float* W1     = (const float*)d_in[1];
    const float* b1     = (const float*)d_in[2];
    const float* gamma_ = (const float*)d_in[3];
    const float* beta_  = (const float*)d_in[4];
    const float* mmean  = (const float*)d_in[5];
    const float* mvar   = (const float*)d_in[6];
    const float* W2     = (const float*)d_in[7];
    const float* b2     = (const float*)d_in[8];
    float* out = (float*)d_out;
    unsigned char* ws = (unsigned char*)d_ws;

    const int Btot = in_sizes[0] / XROW;              // 32768

    divenc_prep<<<QN, 64, 0, stream>>>(W1, b1, gamma_, beta_, mmean, mvar, W2, b2, ws);
    divenc_mfma<<<dim3(Btot / ROWS_BLK, QN / QBLK), 512, 0, stream>>>(x, ws, out);
}

// Round 13
// 52.514 us; speedup vs baseline: 1.0212x; 1.0212x over previous
//
#include <hip/hip_runtime.h>
#include <hip/hip_bf16.h>

// DivEncLayer via MFMA, R13: R6 core + barrier-free depth-3 x-prefetch pipeline.
// per (b,q): z = W1^T x + b1; out = sum_h w2p*elu(z) + b2p.  B=32768, Q=128, S=8, H=32.
//
// R12 -> R13: every prior variant kept <=2 x-loads in flight per wave (R6/R11: load-then-
// consume; R12: vmcnt(0)-drain at each chunk barrier) -> chip-wide outstanding ~1-2MB,
// below the 5.7MB Little's-law floor for 6.3TB/s at ~900ns -> measured 1.1TB/s. Fix:
// ONE barrier per kernel (slab[4][256][9] holds all 4 qg), x loads issued 3 iterations
// ahead into a 4-slot register ring (slot=(sub+3)&3, static even with rolled qg).
// Dual MFMA shares one B (A1 = W1 in k0-7 + zero k8-15, A2 = same bytes at lane^32);
// D0/D1 sequential (16 AGPR); bias via C=cini(b1); elu = E+R-1 with -sum(w2p) in b2p.

#define QN 128
#define SN 8
#define HN 32
#define XROW 1024
#define BN_EPS 1e-3f

typedef short bf16x8 __attribute__((ext_vector_type(8)));
typedef float f32x16 __attribute__((ext_vector_type(16)));
typedef unsigned int u32;

#define WS_A_BYTES (QN * 64 * 16)                 // A[q][lane] 16B (lanes>=32 zero)
#define WS_C_OFF   WS_A_BYTES
#define WS_C_BYTES (QN * 32 * 4)                  // cini[q][half*16+r] = b1 (f32, D-reg order)
#define WS_W_OFF   (WS_C_OFF + WS_C_BYTES)
#define WS_W_BYTES (QN * 32 * 4)                  // w2p[q][half*16+r]
#define WS_B2_OFF  (WS_W_OFF + WS_W_BYTES)        // b2p[q] (with -sum(w2p) folded)

static __device__ __forceinline__ u32 pkbf(float lo, float hi) {
    union { __hip_bfloat162 h2; u32 u; } c;
    c.h2 = __float22bfloat162_rn(float2{lo, hi});
    return c.u;
}

__global__ void divenc_prep(const float* __restrict__ W1, const float* __restrict__ b1,
                            const float* __restrict__ gamma_, const float* __restrict__ beta_,
                            const float* __restrict__ mmean, const float* __restrict__ mvar,
                            const float* __restrict__ W2, const float* __restrict__ b2,
                            unsigned char* __restrict__ ws)
{
    const int q = blockIdx.x;        // 0..127
    const int m = threadIdx.x;       // 0..63

    u32 d0 = 0, d1 = 0, d2 = 0, d3 = 0;
    if (m < 32) {                    // A[m][k0..7] = W1[q][k][m]; lanes>=32 all zero
        d0 = pkbf(W1[(q*SN + 0)*HN + m], W1[(q*SN + 1)*HN + m]);
        d1 = pkbf(W1[(q*SN + 2)*HN + m], W1[(q*SN + 3)*HN + m]);
        d2 = pkbf(W1[(q*SN + 4)*HN + m], W1[(q*SN + 5)*HN + m]);
        d3 = pkbf(W1[(q*SN + 6)*HN + m], W1[(q*SN + 7)*HN + m]);
    }
    ((uint4*)ws)[q*64 + m] = uint4{d0, d1, d2, d3};

    float* wsC  = (float*)(ws + WS_C_OFF);
    float* wsW  = (float*)(ws + WS_W_OFF);
    float* wsB2 = (float*)(ws + WS_B2_OFF);
    if (m < 32) {                    // D-reg order: h = (r&3) + 8*(r>>2) + 4*half
        const int half = m >> 4, r = m & 15;
        const int h = (r & 3) + 8*(r >> 2) + 4*half;
        wsC[q*32 + m] = b1[q*HN + h];
        float inv = gamma_[q*HN+h] * rsqrtf(mvar[q*HN+h] + BN_EPS);
        wsW[q*32 + m] = inv * W2[q*HN + h];
    }
    if (m == 0) {
        float acc = b2[q];
        for (int h = 0; h < HN; ++h) {
            float inv = gamma_[q*HN+h] * rsqrtf(mvar[q*HN+h] + BN_EPS);
            float w2p = inv * W2[q*HN + h];
            acc += (beta_[q*HN+h] - mmean[q*HN+h]*inv) * W2[q*HN+h] - w2p;  // fold -sum(w2p)
        }
        wsB2[q] = acc;
    }
}

__global__ __launch_bounds__(512, 4)
void divenc_mfma(const float* __restrict__ x, const unsigned char* __restrict__ ws,
                 float* __restrict__ out)
{
    const int tid  = threadIdx.x;
    const int lane = tid & 63;
    const int wv   = tid >> 6;       // 0..7
    const int half = lane >> 5;
    const int bl   = lane & 31;
    const int b0   = blockIdx.x * 256;
    const int q0   = blockIdx.y * 32;

    const uint4* wsA  = (const uint4*)ws;
    const float* wsC  = (const float*)(ws + WS_C_OFF);
    const float* wsW  = (const float*)(ws + WS_W_OFF);
    const float* wsB2 = (const float*)(ws + WS_B2_OFF);

    __shared__ float slab[4][256][9];    // 36.9 KiB; ONE barrier at the end

    // addr(qg,sub) = xbase + sub*64*XROW + qg*64   (q step 8 -> 64 floats)
    const float* xbase = x + (size_t)(b0 + lane) * XROW + (q0 + wv) * SN;

    float4 sa[4], sc[4];                 // 4-slot ring, 3 loads in flight
    #pragma unroll
    for (int p = 0; p < 3; ++p) {        // its 0,1,2 = (qg0, sub p) -> slot p
        const float* a = xbase + (size_t)(p * 64) * XROW;
        sa[p] = *(const float4*)a;
        sc[p] = *(const float4*)(a + 4);
    }

    #pragma unroll 1
    for (int qg = 0; qg < 4; ++qg) {
        const int q = q0 + qg*8 + wv;

        union { uint4 u; bf16x8 v; } A1, A2;
        A1.u = wsA[q*64 + lane];          // W1 k0-7 in lanes<32, zeros elsewhere
        A2.u = wsA[q*64 + (lane ^ 32)];   // same bytes -> W1 in k8-15 slots

        f32x16 cini;
        const float* cp_ = wsC + q*32 + half*16;
        #pragma unroll
        for (int r = 0; r < 16; ++r) cini[r] = cp_[r];
        float w2r[16];
        const float* wp_ = wsW + q*32 + half*16;
        #pragma unroll
        for (int r = 0; r < 16; ++r) w2r[r] = wp_[r];
        const float b2p = wsB2[q];

        #pragma unroll
        for (int sub = 0; sub < 4; ++sub) {
            // prefetch it+3 (clamped at the tail: duplicate load of it=15, harmless)
            {
                const int it = qg*4 + sub;
                const int n  = (it + 3 < 16) ? it + 3 : 15;
                const int slot = (sub + 3) & 3;          // == n&3, compile-time
                const float* a = xbase + (size_t)((n & 3) * 64) * XROW + (n >> 2) * 64;
                sa[slot] = *(const float4*)a;
                sc[slot] = *(const float4*)(a + 4);
            }

            union { uint4 u; bf16x8 v; } B;              // consume slot == sub
            B.u = uint4{ pkbf(sa[sub].x, sa[sub].y), pkbf(sa[sub].z, sa[sub].w),
                         pkbf(sc[sub].x, sc[sub].y), pkbf(sc[sub].z, sc[sub].w) };

            // D0 = rows sub*64 + 0..31 (B k0-7 from lanes<32)
            f32x16 D0 = __builtin_amdgcn_mfma_f32_32x32x16_bf16(A1.v, B.v, cini, 0, 0, 0);
            float p0 = 0.f, p0b = 0.f;                   // elu = E + R - 1 (-1 in b2p)
            #pragma unroll
            for (int r = 0; r < 16; ++r) {
                const float z = D0[r];
                const float E = __expf(fminf(z, 0.f));
                const float R = fmaxf(z, 0.f);
                p0  = fmaf(E, w2r[r], p0);
                p0b = fmaf(R, w2r[r], p0b);
            }
            p0 += p0b;
            p0 += __shfl_xor(p0, 32);

            // D1 = rows sub*64 + 32..63 (B k8-15 from lanes>=32)
            f32x16 D1 = __builtin_amdgcn_mfma_f32_32x32x16_bf16(A2.v, B.v, cini, 0, 0, 0);
            float p1 = 0.f, p1b = 0.f;
            #pragma unroll
            for (int r = 0; r < 16; ++r) {
                const float z = D1[r];
                const float E = __expf(fminf(z, 0.f));
                const float R = fmaxf(z, 0.f);
                p1  = fmaf(E, w2r[r], p1);
                p1b = fmaf(R, w2r[r], p1b);
            }
            p1 += p1b;
            p1 += __shfl_xor(p1, 32);

            const float v = (half ? p1 : p0) + b2p;
            slab[qg][sub*64 + half*32 + bl][wv] = v;     // stride 9: 2-way = free
        }
    }

    __syncthreads();                      // the ONLY barrier: vmcnt drains once

    // dump 256 rows x 32 q: thread (row=tid>>1, h16=tid&1) writes 16 cols
    {
        const int row = tid >> 1;
        const int h16 = (tid & 1) * 16;
        float* orow = out + (size_t)(b0 + row) * QN + q0 + h16;
        #pragma unroll
        for (int c4 = 0; c4 < 4; ++c4) {
            const int c = h16 + c4 * 4;                  // cols c..c+3, same qg-slab
            float4 vv;
            vv.x = slab[c >> 3][row][(c & 7) + 0];
            vv.y = slab[c >> 3][row][(c & 7) + 1];
            vv.z = slab[c >> 3][row][(c & 7) + 2];
            vv.w = slab[c >> 3][row][(c & 7) + 3];
            *(float4*)(orow + c4 * 4) = vv;
        }
    }
}

extern "C" void kernel_launch(void* const* d_in, const int* in_sizes, int n_in,
                              void* d_out, int out_size, void* d_ws, size_t ws_size,
                              hipStream_t stream) {
    const float* x      = (const float*)d_in[0];
    const float* W1     = (const float*)d_in[1];
    const float* b1     = (const float*)d_in[2];
    const float* gamma_ = (const float*)d_in[3];
    const float* beta_  = (const float*)d_in[4];
    const float* mmean  = (const float*)d_in[5];
    const float* mvar   = (const float*)d_in[6];
    const float* W2     = (const float*)d_in[7];
    const float* b2     = (const float*)d_in[8];
    float* out = (float*)d_out;
    unsigned char* ws = (unsigned char*)d_ws;

    const int Btot = in_sizes[0] / XROW;              // 32768

    divenc_prep<<<QN, 64, 0, stream>>>(W1, b1, gamma_, beta_, mmean, mvar, W2, b2, ws);
    divenc_mfma<<<dim3(Btot / 256, QN / 32), 512, 0, stream>>>(x, ws, out);
}